// Round 9
// baseline (189.624 us; speedup 1.0000x reference)
//
#include <hip/hip_runtime.h>

#define LDIM 4096
#define DDIM 64
#define KCODES 1024
#define BDIM 16
#define NROWS 65536   // BDIM * LDIM
#define NSLICE 8
#define SLICE_ROWS (NROWS / NSLICE)   // 8192

typedef __attribute__((ext_vector_type(8))) short short8;
typedef __attribute__((ext_vector_type(16))) float float16v;

__device__ __forceinline__ unsigned int orderf(float f) {
  unsigned int u = __float_as_uint(f);
  return (u & 0x80000000u) ? ~u : (u | 0x80000000u);
}

__device__ __forceinline__ unsigned long long shfl_xor_u64(unsigned long long v, int m) {
  int lo = __shfl_xor((int)(unsigned int)(v & 0xffffffffull), m, 64);
  int hi = __shfl_xor((int)(unsigned int)(v >> 32), m, 64);
  return ((unsigned long long)(unsigned int)hi << 32) | (unsigned int)lo;
}

// bf16 RNE high part (as ushort bits)
__device__ __forceinline__ unsigned int bf16_rne(float x) {
  unsigned int u = __float_as_uint(x);
  return (u + 0x7FFFu + ((u >> 16) & 1u)) >> 16;
}

// ---------------------------------------------------------------------------
// prep: per-code norm + softmax table + FRAGMENT-LOAD-ORDER bf16 codebook.
// For tile t (32 codes), load-instruction q (0..3 hi s, 4..7 lo s), lane
// (h*32+m): 8 shorts = B-frag of code c=t*32+m, dims d=16s+8h+[0,8).
// Short index: t*4096 + q*512 + (h*32+m)*8 + j -> wave loads are contiguous
// 1 KB, fully coalesced, sequential through the 256 KB table.
// ---------------------------------------------------------------------------
__global__ void prep_kernel(const float* __restrict__ Ew,
                            float* __restrict__ enorm,
                            float* __restrict__ SE,
                            unsigned short* __restrict__ Epk2) {
  int k = blockIdx.x;
  int d = threadIdx.x;
  float v = Ew[k * DDIM + d];
  float n2 = v * v;
  #pragma unroll
  for (int o = 32; o > 0; o >>= 1) n2 += __shfl_xor(n2, o, 64);
  float m = v;
  #pragma unroll
  for (int o = 32; o > 0; o >>= 1) m = fmaxf(m, __shfl_xor(m, o, 64));
  float e = expf(v - m);
  float Z = e;
  #pragma unroll
  for (int o = 32; o > 0; o >>= 1) Z += __shfl_xor(Z, o, 64);
  SE[k * DDIM + d] = e / Z;
  if (d == 0) enorm[k] = n2;

  unsigned int rh = bf16_rne(v);
  float hif = __uint_as_float(rh << 16);
  unsigned int rl = bf16_rne(v - hif);
  int tile = k >> 5, mm = k & 31;
  int s = d >> 4, h = (d >> 3) & 1, j = d & 7;
  int base = tile * 4096 + (h * 32 + mm) * 8 + j;
  Epk2[base + s * 512]        = (unsigned short)rh;
  Epk2[base + (4 + s) * 512]  = (unsigned short)rl;
}

// ---------------------------------------------------------------------------
// FUSED argmin + quantize + KL. One wave owns 32 rows end-to-end:
//  1. x loaded once: fp32 in xr[32] + bf16 hi/lo A-frags.
//  2. MFMA argmin over the fragment-linear codebook (coalesced 1 KB loads,
//     register double-buffer, 3 independent accumulator chains).
//  3. Per-row best via butterfly; k's dropped in a 512 B LDS kbuf (wave-
//     synchronous round-trip, no barrier) so lane (m,h) gets k[row m].
//  4. Epilogue from registers: gather Ew[k]/SE[k] (L2-hot), write quantized
//     out (coalesced 2x128 B per instr), one KL atomic per wave.
// score = ||E||^2 - 2 x.E  (row-constant ||x||^2 dropped; order/ties kept).
// ---------------------------------------------------------------------------
__launch_bounds__(256, 2)
__global__ void argmin_fused_kernel(const float* __restrict__ inp,
                                    const unsigned short* __restrict__ Epk2,
                                    const float* __restrict__ enorm,
                                    const float* __restrict__ Ew,
                                    const float* __restrict__ SE,
                                    int* __restrict__ idx_ws,
                                    float* __restrict__ outidx,
                                    float* __restrict__ out,
                                    float* __restrict__ klacc) {
  __shared__ int kbuf[4][32];

  const int tid = threadIdx.x;
  const int lane = tid & 63;
  const int w = tid >> 6;
  const int half = lane >> 5;
  const int m = lane & 31;
  const int row_base = blockIdx.x * 128 + w * 32;
  const int b = row_base >> 12;
  const int l0 = row_base & 4095;
  const float* xp = inp + (size_t)b * DDIM * LDIM + l0 + m;
  float* op = out + (size_t)b * DDIM * LDIM + l0 + m;

  // ---- x once: fp32 regs + bf16 hi/lo A-frags --------------------------
  // lane (m,h) holds row m, dims d = 16s + 8h + j  (s=0..3, j=0..7)
  float xr[32];
  short8 afr[8];   // 0..3 = hi frags, 4..7 = lo frags
  #pragma unroll
  for (int s = 0; s < 4; s++) {
    #pragma unroll
    for (int j = 0; j < 8; j++) {
      int d = 16 * s + 8 * half + j;
      float x = xp[(size_t)d * LDIM];
      xr[s * 8 + j] = x;
      unsigned int rh = bf16_rne(x);
      float hif = __uint_as_float(rh << 16);
      unsigned int rl = bf16_rne(x - hif);
      afr[s][j] = (short)(unsigned short)rh;
      afr[4 + s][j] = (short)(unsigned short)rl;
    }
  }

  float bsc[16];
  int bix[16];
  #pragma unroll
  for (int j = 0; j < 16; j++) { bsc[j] = 1e30f; bix[j] = 0; }

  const unsigned short* eb = Epk2 + lane * 8;

  short8 bA[8], bB[8];
  float enA, enB;

  #pragma unroll
  for (int s = 0; s < 4; s++) {
    bA[s]     = *(const short8*)(eb + s * 512);
    bA[4 + s] = *(const short8*)(eb + 2048 + s * 512);
  }
  enA = enorm[m];

  #pragma unroll 1
  for (int i = 0; i < 16; i++) {
    const int tB = 2 * i + 1;
    {
      const unsigned short* p = eb + tB * 4096;
      #pragma unroll
      for (int s = 0; s < 4; s++) {
        bB[s]     = *(const short8*)(p + s * 512);
        bB[4 + s] = *(const short8*)(p + 2048 + s * 512);
      }
      enB = enorm[tB * 32 + m];
    }
    {
      float16v a0 = {}, a1 = {}, a2 = {};
      #pragma unroll
      for (int s = 0; s < 4; s++) {
        a0 = __builtin_amdgcn_mfma_f32_32x32x16_bf16(afr[s], bA[s], a0, 0, 0, 0);
        a1 = __builtin_amdgcn_mfma_f32_32x32x16_bf16(afr[s], bA[4 + s], a1, 0, 0, 0);
        a2 = __builtin_amdgcn_mfma_f32_32x32x16_bf16(afr[4 + s], bA[s], a2, 0, 0, 0);
      }
      int ci = 2 * i * 32 + m;
      #pragma unroll
      for (int j = 0; j < 16; j++) {
        float sc = fmaf(-2.f, a0[j] + a1[j] + a2[j], enA);
        if (sc < bsc[j]) { bsc[j] = sc; bix[j] = ci; }  // ascending ci: ties -> smaller
      }
    }
    if (i < 15) {
      const unsigned short* p = eb + (2 * i + 2) * 4096;
      #pragma unroll
      for (int s = 0; s < 4; s++) {
        bA[s]     = *(const short8*)(p + s * 512);
        bA[4 + s] = *(const short8*)(p + 2048 + s * 512);
      }
      enA = enorm[(2 * i + 2) * 32 + m];
    }
    {
      float16v a0 = {}, a1 = {}, a2 = {};
      #pragma unroll
      for (int s = 0; s < 4; s++) {
        a0 = __builtin_amdgcn_mfma_f32_32x32x16_bf16(afr[s], bB[s], a0, 0, 0, 0);
        a1 = __builtin_amdgcn_mfma_f32_32x32x16_bf16(afr[s], bB[4 + s], a1, 0, 0, 0);
        a2 = __builtin_amdgcn_mfma_f32_32x32x16_bf16(afr[4 + s], bB[s], a2, 0, 0, 0);
      }
      int ci = tB * 32 + m;
      #pragma unroll
      for (int j = 0; j < 16; j++) {
        float sc = fmaf(-2.f, a0[j] + a1[j] + a2[j], enB);
        if (sc < bsc[j]) { bsc[j] = sc; bix[j] = ci; }
      }
    }
  }

  // C layout: row = (j&3)+8*(j>>2)+4*half, col = m. Butterfly min over cols
  // leaves the min in all 32 lanes of the half; m==0 publishes.
  #pragma unroll
  for (int j = 0; j < 16; j++) {
    unsigned long long key =
        ((unsigned long long)orderf(bsc[j]) << 32) | (unsigned int)bix[j];
    #pragma unroll
    for (int mm = 1; mm < 32; mm <<= 1) {
      unsigned long long o = shfl_xor_u64(key, mm);
      if (o < key) key = o;
    }
    if (m == 0) {
      int row_local = (j & 3) + 8 * (j >> 2) + 4 * half;
      int grow = row_base + row_local;
      int cidx = (int)(key & 0xffffffffull);
      idx_ws[grow] = cidx;
      outidx[grow] = (float)cidx;
      kbuf[w][row_local] = cidx;
    }
  }

  // wave-synchronous LDS round-trip (same wave wrote it; no barrier needed)
  const int km = kbuf[w][m];

  // ---- epilogue: quantized out + KL, all from registers + L2 gathers ----
  const float* SEk = SE + km * DDIM + 8 * half;
  const float* Ewk = Ew + km * DDIM + 8 * half;
  float Zh = 0.f, S1h = 0.f, Uh = 0.f;
  #pragma unroll
  for (int s = 0; s < 4; s++) {
    float qv[8], ev[8];
    *(float4*)&qv[0] = *(const float4*)(SEk + 16 * s);
    *(float4*)&qv[4] = *(const float4*)(SEk + 16 * s + 4);
    *(float4*)&ev[0] = *(const float4*)(Ewk + 16 * s);
    *(float4*)&ev[4] = *(const float4*)(Ewk + 16 * s + 4);
    #pragma unroll
    for (int j = 0; j < 8; j++) {
      float x = xr[s * 8 + j];
      float e = expf(x);
      Zh += e;
      S1h += e * x;
      Uh += e * qv[j];
      op[(size_t)(16 * s + 8 * half + j) * LDIM] = ev[j];
    }
  }
  float Zt = Zh + __shfl_xor(Zh, 32, 64);
  float S1t = S1h + __shfl_xor(S1h, 32, 64);
  float Ut = Uh + __shfl_xor(Uh, 32, 64);
  float kl = (half == 0) ? ((S1t - Ut) / Zt - logf(Zt)) : 0.f;
  #pragma unroll
  for (int o = 32; o > 0; o >>= 1) kl += __shfl_xor(kl, o, 64);
  if (lane == 0) atomicAdd(klacc, kl);
}

// ---------------------------------------------------------------------------
// dw partial: dimension-sliced histogram, 512 thr/block; d==0 blocks also
// histogram counts. Zero global atomics.
// ---------------------------------------------------------------------------
__launch_bounds__(512)
__global__ void dw_partial_kernel(const float* __restrict__ inp,
                                  const int* __restrict__ idx_ws,
                                  float* __restrict__ partial,
                                  float* __restrict__ pcounts) {
  __shared__ float dwp[KCODES];
  __shared__ float cnt[KCODES];
  const int d = blockIdx.x & 63;
  const int slice = blockIdx.x >> 6;
  const int tid = threadIdx.x;
  const bool do_cnt = (d == 0);

  #pragma unroll
  for (int i = 0; i < KCODES / 512; i++) {
    dwp[tid + i * 512] = 0.f;
    cnt[tid + i * 512] = 0.f;
  }
  __syncthreads();

  const int r0 = slice * SLICE_ROWS;
  for (int i = tid; i < SLICE_ROWS; i += 512) {
    int r = r0 + i;
    int b = r >> 12, l = r & 4095;
    float x = inp[(size_t)b * DDIM * LDIM + (size_t)d * LDIM + l];
    int k = idx_ws[r];
    atomicAdd(&dwp[k], x);
    if (do_cnt) atomicAdd(&cnt[k], 1.0f);
  }
  __syncthreads();

  float* dst = partial + ((size_t)slice * 64 + d) * KCODES;
  #pragma unroll
  for (int i = 0; i < KCODES / 512; i++) dst[tid + i * 512] = dwp[tid + i * 512];
  if (do_cnt) {
    float* cd = pcounts + (size_t)slice * KCODES;
    #pragma unroll
    for (int i = 0; i < KCODES / 512; i++) cd[tid + i * 512] = cnt[tid + i * 512];
  }
}

// ---------------------------------------------------------------------------
// csp + perplexity (from count partials). 1 block x 1024.
// ---------------------------------------------------------------------------
__global__ void csp_kernel(const float* __restrict__ ema_cs,
                           const float* __restrict__ pcounts,
                           float* __restrict__ csp,
                           float* __restrict__ perp_out) {
  __shared__ float red1[16], red2[16];
  int k = threadIdx.x;
  float c = 0.f;
  #pragma unroll
  for (int sl = 0; sl < NSLICE; sl++) c += pcounts[sl * KCODES + k];
  float cs = ema_cs[k] * 0.9f + 0.1f * c;
  float n = cs;
  #pragma unroll
  for (int o = 32; o > 0; o >>= 1) n += __shfl_xor(n, o, 64);
  if ((k & 63) == 0) red1[k >> 6] = n;
  float a = c * (1.0f / 65536.0f);
  float ent = a * logf(a + 1e-10f);
  float es = ent;
  #pragma unroll
  for (int o = 32; o > 0; o >>= 1) es += __shfl_xor(es, o, 64);
  if ((k & 63) == 0) red2[k >> 6] = es;
  __syncthreads();
  if (k == 0) {
    float t1 = 0.f, t2 = 0.f;
    for (int i = 0; i < 16; i++) { t1 += red1[i]; t2 += red2[i]; }
    red1[0] = t1;
    *perp_out = expf(-t2);
  }
  __syncthreads();
  float N = red1[0];
  csp[k] = (cs + 1e-5f) / (N + 1024.0f * 1e-5f) * N;
}

// ---------------------------------------------------------------------------
// reduce partials + embed epilogue + loss scalar.
// ---------------------------------------------------------------------------
__launch_bounds__(256)
__global__ void reduce_embed_kernel(const float* __restrict__ partial,
                                    const float* __restrict__ emaw,
                                    const float* __restrict__ csp,
                                    const float* __restrict__ klacc,
                                    float* __restrict__ emb_out,
                                    float* __restrict__ loss_out) {
  int i = blockIdx.x * 256 + threadIdx.x;
  int k = i >> 6, d = i & 63;
  float s = 0.f;
  #pragma unroll
  for (int sl = 0; sl < NSLICE; sl++)
    s += partial[((size_t)sl * 64 + d) * KCODES + k];
  float v = fmaf(0.1f, s, emaw[i] * 0.9f);
  emb_out[i] = v / csp[k];
  if (i == 0) *loss_out = 0.1f * (*klacc) * (1.0f / 16.0f);
}

extern "C" void kernel_launch(void* const* d_in, const int* in_sizes, int n_in,
                              void* d_out, int out_size, void* d_ws, size_t ws_size,
                              hipStream_t stream) {
  const float* inp   = (const float*)d_in[0];   // (16,64,4096)
  const float* Ew    = (const float*)d_in[1];   // (1024,64)
  const float* emacs = (const float*)d_in[2];   // (1024,)
  const float* emaw  = (const float*)d_in[3];   // (1024,64)

  float* out      = (float*)d_out;              // (16,64,4096) = 4194304
  float* loss_out = out + 4194304;
  float* perp_out = out + 4194305;
  float* emb_out  = out + 4194306;              // 65536
  float* idxf_out = out + 4194306 + 65536;      // 65536 (indices as float)

  char* ws = (char*)d_ws;
  int*   idx_ws  = (int*)(ws);                  // 262144 B
  float* klacc   = (float*)(ws + 262144);       // 256 B (zeroed)
  float* enorm   = (float*)(ws + 266496);       // 4096 B
  float* csp     = (float*)(ws + 270592);       // 4096 B
  float* SE      = (float*)(ws + 274688);       // 262144 B -> ends 536832
  unsigned short* Epk2 = (unsigned short*)(ws + 536832);  // 262144 B
  // dw partials alias Epk2 (dead after argmin_fused)
  float* partial = (float*)(ws + 536832);       // 2097152 B -> ends 2633984
  float* pcounts = (float*)(ws + 2633984);      // 32768 B  -> ends 2666752

  hipMemsetAsync(ws + 262144, 0, 256, stream);

  prep_kernel<<<KCODES, 64, 0, stream>>>(Ew, enorm, SE, Epk2);
  argmin_fused_kernel<<<512, 256, 0, stream>>>(inp, Epk2, enorm, Ew, SE,
                                               idx_ws, idxf_out, out, klacc);
  dw_partial_kernel<<<64 * NSLICE, 512, 0, stream>>>(inp, idx_ws, partial, pcounts);
  csp_kernel<<<1, 1024, 0, stream>>>(emacs, pcounts, csp, perp_out);
  reduce_embed_kernel<<<NROWS / 256, 256, 0, stream>>>(partial, emaw, csp, klacc,
                                                       emb_out, loss_out);
}